// Round 6
// baseline (146.144 us; speedup 1.0000x reference)
//
#include <hip/hip_runtime.h>
#include <hip/hip_bf16.h>
#include <stdint.h>

// Problem constants
#define B_    4
#define CQ_   256
#define CKV_  256
#define NQ_   2048
#define NKV_  2048
#define H_    8
#define DK_   64
#define HD_   512   // H_*DK_

typedef __attribute__((ext_vector_type(8))) short bf16x8;
typedef __attribute__((ext_vector_type(4))) float f32x4;

__device__ __forceinline__ short f2bf(float f) {
    unsigned u = __builtin_bit_cast(unsigned, f);
    u = (u + 0x7FFFu + ((u >> 16) & 1u)) >> 16;   // RNE truncate to bf16
    return (short)u;
}

#define MFMA16(a, b, c) __builtin_amdgcn_mfma_f32_16x16x32_bf16((a), (b), (c), 0, 0, 0)

// -------------------------------------------------------------------------
// Kernel 1: prep + pq fused.
//  [0,1024):    x_kv f32 -> xkv_bf bf16
//  [1024,1536): x_q [b][cq][n] -> xqt_bf [b][n][cq] (transpose, bf16)
//  [1536,1664): pq folds (P = Wo_h*Wv_h stacked; Qt = Wq^T*Wk per h)
// -------------------------------------------------------------------------
__global__ __launch_bounds__(256) void prep_pq_kernel(
    const float* __restrict__ x_kv,
    const float* __restrict__ x_q,
    const float* __restrict__ Wq,
    const float* __restrict__ Wk,
    const float* __restrict__ Wv,
    const float* __restrict__ Wo,
    unsigned short* __restrict__ xkv_bf,
    unsigned short* __restrict__ xqt_bf,
    unsigned short* __restrict__ P,
    unsigned short* __restrict__ Qt)
{
    const int tid = threadIdx.x;
    int bid = blockIdx.x;
    if (bid < 1024) {
        const size_t base = ((size_t)bid * 256 + tid) * 8;
        const f32x4 v0 = *(const f32x4*)(x_kv + base);
        const f32x4 v1 = *(const f32x4*)(x_kv + base + 4);
        bf16x8 o;
        o[0] = f2bf(v0.x); o[1] = f2bf(v0.y); o[2] = f2bf(v0.z); o[3] = f2bf(v0.w);
        o[4] = f2bf(v1.x); o[5] = f2bf(v1.y); o[6] = f2bf(v1.z); o[7] = f2bf(v1.w);
        *(bf16x8*)(xkv_bf + base) = o;
        return;
    }
    if (bid < 1536) {
        bid -= 1024;
        const int b   = bid >> 7;
        const int t   = bid & 127;
        const int cq0 = (t & 3) * 64;
        const int n0  = (t >> 2) * 64;

        __shared__ float tile[64][65];
        const float* src = x_q + (size_t)b * CQ_ * NQ_;
        const int r_l = tid >> 4;
        const int c_l = (tid & 15) * 4;
#pragma unroll
        for (int i = 0; i < 4; ++i) {
            const int row = r_l + 16 * i;
            const f32x4 v = *(const f32x4*)(src + (size_t)(cq0 + row) * NQ_ + n0 + c_l);
            tile[row][c_l] = v.x; tile[row][c_l + 1] = v.y;
            tile[row][c_l + 2] = v.z; tile[row][c_l + 3] = v.w;
        }
        __syncthreads();
        unsigned short* dst = xqt_bf + (size_t)b * NQ_ * CQ_;
        const int cq_l = (tid & 7) * 8;
#pragma unroll
        for (int j = 0; j < 2; ++j) {
            const int n_l = (tid >> 3) + 32 * j;
            bf16x8 o;
#pragma unroll
            for (int k = 0; k < 8; ++k) o[k] = f2bf(tile[cq_l + k][n_l]);
            *(bf16x8*)(dst + (size_t)(n0 + n_l) * CQ_ + cq0 + cq_l) = o;
        }
        return;
    }

    // ---- pq part ----
    const int lb0 = bid - 1536;
    const bool isP = (lb0 < 64);
    const int lb = isP ? lb0 : lb0 - 64;
    const int h = lb >> 3;
    const int t = lb & 7;
    const int tm = (t >> 1) * 64;
    const int tn = (t & 1) * 128;
    const int w = tid >> 6, L = tid & 63;
    const int r16 = L & 15, q = L >> 4;
    const int wm = (w >> 1) * 32, wn = (w & 1) * 64;

    f32x4 acc[2][4];
#pragma unroll
    for (int mi = 0; mi < 2; ++mi)
#pragma unroll
        for (int ni = 0; ni < 4; ++ni) acc[mi][ni] = (f32x4){0.f,0.f,0.f,0.f};

#pragma unroll
    for (int kk = 0; kk < 2; ++kk) {
        const int d0 = kk * 32 + q * 8;
        bf16x8 a[2], bb[4];
        if (isP) {
#pragma unroll
            for (int mi = 0; mi < 2; ++mi) {
                const int m = tm + wm + mi * 16 + r16;
                const f32x4* p = (const f32x4*)(Wo + (size_t)m * HD_ + h * 64 + d0);
                f32x4 v0 = p[0], v1 = p[1];
                a[mi][0]=f2bf(v0.x); a[mi][1]=f2bf(v0.y); a[mi][2]=f2bf(v0.z); a[mi][3]=f2bf(v0.w);
                a[mi][4]=f2bf(v1.x); a[mi][5]=f2bf(v1.y); a[mi][6]=f2bf(v1.z); a[mi][7]=f2bf(v1.w);
            }
#pragma unroll
            for (int ni = 0; ni < 4; ++ni) {
                const int n = tn + wn + ni * 16 + r16;
#pragma unroll
                for (int j = 0; j < 8; ++j)
                    bb[ni][j] = f2bf(Wv[(size_t)(h * 64 + d0 + j) * CKV_ + n]);
            }
        } else {
#pragma unroll
            for (int mi = 0; mi < 2; ++mi) {
                const int m = tm + wm + mi * 16 + r16;
#pragma unroll
                for (int j = 0; j < 8; ++j)
                    a[mi][j] = f2bf(Wq[(size_t)(h * 64 + d0 + j) * CQ_ + m]);
            }
#pragma unroll
            for (int ni = 0; ni < 4; ++ni) {
                const int n = tn + wn + ni * 16 + r16;
#pragma unroll
                for (int j = 0; j < 8; ++j)
                    bb[ni][j] = f2bf(Wk[(size_t)(h * 64 + d0 + j) * CKV_ + n]);
            }
        }
#pragma unroll
        for (int mi = 0; mi < 2; ++mi)
#pragma unroll
            for (int ni = 0; ni < 4; ++ni)
                acc[mi][ni] = MFMA16(a[mi], bb[ni], acc[mi][ni]);
    }

#pragma unroll
    for (int mi = 0; mi < 2; ++mi)
#pragma unroll
        for (int ni = 0; ni < 4; ++ni)
#pragma unroll
            for (int r = 0; r < 4; ++r) {
                const int m = tm + wm + mi * 16 + q * 4 + r;
                const int n = tn + wn + ni * 16 + r16;
                if (isP)  P [(size_t)m * 2048 + h * 256 + n] = (unsigned short)f2bf(acc[mi][ni][r]);
                else      Qt[((size_t)h * 256 + m) * 256 + n] = (unsigned short)f2bf(acc[mi][ni][r]);
            }
}

// -------------------------------------------------------------------------
// Kernel 2: gram_full.  Gsum_b[c][c'] = (1/64)*sum_{n=0..2047} x[c][n]*x[c'][n]
// Full-K, no partials.  32(c) x 64(c') tiles, grid (8,4,4)=128 blocks.
// 4 waves: wave tile 16x32 (wm 2 x wn 2).  Double-buffered K-loop (64 steps).
// Output bf16 directly (single f32 accumulation chain).
// -------------------------------------------------------------------------
__global__ __launch_bounds__(256) void gram_full_kernel(
    const unsigned short* __restrict__ xkv_bf,
    unsigned short* __restrict__ Gsum)
{
    const int mt = blockIdx.x;   // 0..7   c-tile (32 rows)
    const int nt = blockIdx.y;   // 0..3   c'-tile (64 cols)
    const int b  = blockIdx.z;
    const int tid = threadIdx.x;
    const int w = tid >> 6, L = tid & 63;
    const int r16 = L & 15, q = L >> 4;
    const int wm = (w >> 1) * 16;   // 0,16
    const int wn = (w & 1) * 32;    // 0,32

    const unsigned short* Xb = xkv_bf + (size_t)b * CKV_ * NKV_;
    const unsigned short* A0 = Xb + (size_t)(mt * 32 + wm + r16) * NKV_;
    const unsigned short* B0 = Xb + (size_t)(nt * 64 + wn + r16) * NKV_;
    const unsigned short* B1 = B0 + (size_t)16 * NKV_;
    const int k0 = q * 8;

    f32x4 acc[2];
    acc[0] = (f32x4){0.f,0.f,0.f,0.f};
    acc[1] = (f32x4){0.f,0.f,0.f,0.f};

    bf16x8 aC = *(const bf16x8*)(A0 + k0);
    bf16x8 bC0 = *(const bf16x8*)(B0 + k0);
    bf16x8 bC1 = *(const bf16x8*)(B1 + k0);

#pragma unroll 4
    for (int kk = 1; kk < 64; ++kk) {
        const int ko = k0 + kk * 32;
        bf16x8 aN  = *(const bf16x8*)(A0 + ko);
        bf16x8 bN0 = *(const bf16x8*)(B0 + ko);
        bf16x8 bN1 = *(const bf16x8*)(B1 + ko);
        acc[0] = MFMA16(aC, bC0, acc[0]);
        acc[1] = MFMA16(aC, bC1, acc[1]);
        aC = aN; bC0 = bN0; bC1 = bN1;
    }
    acc[0] = MFMA16(aC, bC0, acc[0]);
    acc[1] = MFMA16(aC, bC1, acc[1]);

    unsigned short* Gb = Gsum + (size_t)b * 65536;
    const float sc = 1.0f / 64.0f;
#pragma unroll
    for (int ni = 0; ni < 2; ++ni)
#pragma unroll
        for (int r = 0; r < 4; ++r) {
            const int row = mt * 32 + wm + q * 4 + r;
            const int col = nt * 64 + wn + ni * 16 + r16;
            Gb[row * 256 + col] = (unsigned short)f2bf(acc[ni][r] * sc);
        }
}

// -------------------------------------------------------------------------
// Kernel 3: zgemm.  Zt_b[cq][h*256+c'] = sum_{c''} Qt[(h,cq)][c'']*Gs_b[c'][c'']
// (G symmetry: B rows contiguous).  64x64 tiles, grid (16,8,4)=512 blocks.
// -------------------------------------------------------------------------
__global__ __launch_bounds__(256) void zgemm_kernel(
    const unsigned short* __restrict__ Qt,
    const unsigned short* __restrict__ Gsum,
    unsigned short* __restrict__ Zt)
{
    const int t = blockIdx.x;   // 0..15
    const int h = blockIdx.y;
    const int b = blockIdx.z;
    const int tid = threadIdx.x;
    const int w = tid >> 6, L = tid & 63;
    const int r16 = L & 15, q = L >> 4;
    const int tm = (t >> 2) * 64;
    const int tn = (t & 3) * 64;
    const int wm = (w >> 1) * 32, wn = (w & 1) * 32;

    const unsigned short* Qh = Qt + (size_t)h * 65536;
    const unsigned short* Gb = Gsum + (size_t)b * 65536;
    const unsigned short* A0 = Qh + (size_t)(tm + wm + r16) * 256;
    const unsigned short* A1 = A0 + 16 * 256;
    const unsigned short* B0 = Gb + (size_t)(tn + wn + r16) * 256;
    const unsigned short* B1 = B0 + 16 * 256;
    const int k0 = q * 8;

    f32x4 acc[2][2];
#pragma unroll
    for (int mi = 0; mi < 2; ++mi)
#pragma unroll
        for (int ni = 0; ni < 2; ++ni) acc[mi][ni] = (f32x4){0.f,0.f,0.f,0.f};

    bf16x8 aC[2], bC[2];
    aC[0] = *(const bf16x8*)(A0 + k0);
    aC[1] = *(const bf16x8*)(A1 + k0);
    bC[0] = *(const bf16x8*)(B0 + k0);
    bC[1] = *(const bf16x8*)(B1 + k0);

#pragma unroll
    for (int kk = 0; kk < 8; ++kk) {
        bf16x8 aN[2], bN[2];
        if (kk < 7) {
            const int ko = k0 + (kk + 1) * 32;
            aN[0] = *(const bf16x8*)(A0 + ko);
            aN[1] = *(const bf16x8*)(A1 + ko);
            bN[0] = *(const bf16x8*)(B0 + ko);
            bN[1] = *(const bf16x8*)(B1 + ko);
        }
        acc[0][0] = MFMA16(aC[0], bC[0], acc[0][0]);
        acc[0][1] = MFMA16(aC[0], bC[1], acc[0][1]);
        acc[1][0] = MFMA16(aC[1], bC[0], acc[1][0]);
        acc[1][1] = MFMA16(aC[1], bC[1], acc[1][1]);
        aC[0] = aN[0]; aC[1] = aN[1]; bC[0] = bN[0]; bC[1] = bN[1];
    }

    unsigned short* Zb = Zt + (size_t)b * 256 * 2048;
#pragma unroll
    for (int mi = 0; mi < 2; ++mi)
#pragma unroll
        for (int ni = 0; ni < 2; ++ni)
#pragma unroll
            for (int r = 0; r < 4; ++r) {
                const int m = tm + wm + mi * 16 + q * 4 + r;       // cq
                const int n = tn + wn + ni * 16 + r16;             // c'
                Zb[(size_t)m * 2048 + h * 256 + n] = (unsigned short)f2bf(acc[mi][ni][r]);
            }
}

// -------------------------------------------------------------------------
// Kernel 4: ngemm_full.  Nbf_b[c][cq] = sum_{k=0..2047} P[c][k]*Zt_b[cq][k]
// Full-K, no partials.  32(c) x 64(cq) tiles, grid (8,4,4)=128 blocks.
// 4 waves: wave tile 16x32.  Double-buffered K-loop (64 steps).  bf16 out.
// -------------------------------------------------------------------------
__global__ __launch_bounds__(256) void ngemm_full_kernel(
    const unsigned short* __restrict__ P,
    const unsigned short* __restrict__ Zt,
    unsigned short* __restrict__ Nbf)
{
    const int mt = blockIdx.x;   // 0..7   c-tile (32 rows)
    const int nt = blockIdx.y;   // 0..3   cq-tile (64 cols)
    const int b  = blockIdx.z;
    const int tid = threadIdx.x;
    const int w = tid >> 6, L = tid & 63;
    const int r16 = L & 15, q = L >> 4;
    const int wm = (w >> 1) * 16;
    const int wn = (w & 1) * 32;

    const unsigned short* Zb = Zt + (size_t)b * 256 * 2048;
    const unsigned short* A0 = P  + (size_t)(mt * 32 + wm + r16) * 2048;
    const unsigned short* B0 = Zb + (size_t)(nt * 64 + wn + r16) * 2048;
    const unsigned short* B1 = B0 + (size_t)16 * 2048;
    const int k0 = q * 8;

    f32x4 acc[2];
    acc[0] = (f32x4){0.f,0.f,0.f,0.f};
    acc[1] = (f32x4){0.f,0.f,0.f,0.f};

    bf16x8 aC = *(const bf16x8*)(A0 + k0);
    bf16x8 bC0 = *(const bf16x8*)(B0 + k0);
    bf16x8 bC1 = *(const bf16x8*)(B1 + k0);

#pragma unroll 4
    for (int kk = 1; kk < 64; ++kk) {
        const int ko = k0 + kk * 32;
        bf16x8 aN  = *(const bf16x8*)(A0 + ko);
        bf16x8 bN0 = *(const bf16x8*)(B0 + ko);
        bf16x8 bN1 = *(const bf16x8*)(B1 + ko);
        acc[0] = MFMA16(aC, bC0, acc[0]);
        acc[1] = MFMA16(aC, bC1, acc[1]);
        aC = aN; bC0 = bN0; bC1 = bN1;
    }
    acc[0] = MFMA16(aC, bC0, acc[0]);
    acc[1] = MFMA16(aC, bC1, acc[1]);

    unsigned short* Nb = Nbf + (size_t)b * 65536;
#pragma unroll
    for (int ni = 0; ni < 2; ++ni)
#pragma unroll
        for (int r = 0; r < 4; ++r) {
            const int row = mt * 32 + wm + q * 4 + r;              // c
            const int col = nt * 64 + wn + ni * 16 + r16;          // cq
            Nb[row * 256 + col] = (unsigned short)f2bf(acc[ni][r]);
        }
}

// -------------------------------------------------------------------------
// Kernel 5: final.  out[b][c][n] = g*sum_cq Nbf[b][c][cq]*xqt[b][n][cq] + x_q[b][c][n]
// 64x64 tiles, grid (32,4,4)=512 blocks.  Double-buffered K-loop.
// -------------------------------------------------------------------------
__global__ __launch_bounds__(256) void final_kernel(
    const unsigned short* __restrict__ Nbf,
    const unsigned short* __restrict__ xqt_bf,
    const float* __restrict__ x_q,
    const float* __restrict__ gamma,
    float* __restrict__ out)
{
    const int nblk = blockIdx.x * 64;
    const int cblk = blockIdx.y * 64;
    const int b    = blockIdx.z;
    const int tid  = threadIdx.x;
    const int w = tid >> 6, L = tid & 63;
    const int r16 = L & 15, q = L >> 4;
    const int wc = (w >> 1) * 32;
    const int wn = (w & 1) * 32;

    const unsigned short* Nb = Nbf + (size_t)b * 65536;
    const unsigned short* Xq = xqt_bf + (size_t)b * NQ_ * CQ_;
    const float* Xb = x_q + (size_t)b * CQ_ * NQ_;
    const float g = gamma[0];

    const unsigned short* A0 = Nb + (size_t)(cblk + wc + r16) * 256;
    const unsigned short* A1 = A0 + 16 * 256;
    const unsigned short* B0 = Xq + (size_t)(nblk + wn + r16) * 256;
    const unsigned short* B1 = B0 + 16 * 256;
    const int k0 = q * 8;

    f32x4 acc[2][2];
#pragma unroll
    for (int mi = 0; mi < 2; ++mi)
#pragma unroll
        for (int ni = 0; ni < 2; ++ni) acc[mi][ni] = (f32x4){0.f,0.f,0.f,0.f};

    bf16x8 aC[2], bC[2];
    aC[0] = *(const bf16x8*)(A0 + k0);
    aC[1] = *(const bf16x8*)(A1 + k0);
    bC[0] = *(const bf16x8*)(B0 + k0);
    bC[1] = *(const bf16x8*)(B1 + k0);

#pragma unroll
    for (int kk = 0; kk < 8; ++kk) {
        bf16x8 aN[2], bN[2];
        if (kk < 7) {
            const int ko = k0 + (kk + 1) * 32;
            aN[0] = *(const bf16x8*)(A0 + ko);
            aN[1] = *(const bf16x8*)(A1 + ko);
            bN[0] = *(const bf16x8*)(B0 + ko);
            bN[1] = *(const bf16x8*)(B1 + ko);
        }
        acc[0][0] = MFMA16(aC[0], bC[0], acc[0][0]);
        acc[0][1] = MFMA16(aC[0], bC[1], acc[0][1]);
        acc[1][0] = MFMA16(aC[1], bC[0], acc[1][0]);
        acc[1][1] = MFMA16(aC[1], bC[1], acc[1][1]);
        aC[0] = aN[0]; aC[1] = aN[1]; bC[0] = bN[0]; bC[1] = bN[1];
    }

#pragma unroll
    for (int mi = 0; mi < 2; ++mi)
#pragma unroll
        for (int ni = 0; ni < 2; ++ni)
#pragma unroll
            for (int r = 0; r < 4; ++r) {
                const int c = cblk + wc + mi * 16 + q * 4 + r;
                const int n = nblk + wn + ni * 16 + r16;
                const size_t idx = ((size_t)b * CQ_ + c) * NQ_ + n;
                out[idx] = g * acc[mi][ni][r] + Xb[(size_t)c * NQ_ + n];
            }
}

// -------------------------------------------------------------------------
extern "C" void kernel_launch(void* const* d_in, const int* in_sizes, int n_in,
                              void* d_out, int out_size, void* d_ws, size_t ws_size,
                              hipStream_t stream) {
    const float* x_q   = (const float*)d_in[0];
    const float* x_kv  = (const float*)d_in[1];
    const float* Wq    = (const float*)d_in[2];
    const float* Wk    = (const float*)d_in[3];
    const float* Wv    = (const float*)d_in[4];
    const float* Wo    = (const float*)d_in[5];
    const float* gamma = (const float*)d_in[6];
    float* out = (float*)d_out;

    char* ws = (char*)d_ws;
    // ws layout (bytes):
    //   xkv_bf bf16 [4][256][2048]        0 ..  4194304
    //   xqt_bf bf16 [4][2048][256]  4194304 ..  8388608
    //   Gsum   bf16 [4][256][256]   8388608 ..  8912896
    //   P      bf16 [256][2048]     8912896 ..  9961472
    //   Qt     bf16 [8][256][256]   9961472 .. 11010048
    //   Zt     bf16 [4][256][2048] 11010048 .. 15204352
    //   Nbf    bf16 [4][256][256]  15204352 .. 15728640
    unsigned short* xkv_bf = (unsigned short*)(ws);
    unsigned short* xqt_bf = (unsigned short*)(ws + 4194304);
    unsigned short* Gsum   = (unsigned short*)(ws + 8388608);
    unsigned short* P      = (unsigned short*)(ws + 8912896);
    unsigned short* Qt     = (unsigned short*)(ws + 9961472);
    unsigned short* Zt     = (unsigned short*)(ws + 11010048);
    unsigned short* Nbf    = (unsigned short*)(ws + 15204352);

    prep_pq_kernel<<<dim3(1664), 256, 0, stream>>>(x_kv, x_q, Wq, Wk, Wv, Wo,
                                                   xkv_bf, xqt_bf, P, Qt);
    gram_full_kernel<<<dim3(8, 4, 4), 256, 0, stream>>>(xkv_bf, Gsum);
    zgemm_kernel<<<dim3(16, 8, 4), 256, 0, stream>>>(Qt, Gsum, Zt);
    ngemm_full_kernel<<<dim3(8, 4, 4), 256, 0, stream>>>(P, Zt, Nbf);
    final_kernel<<<dim3(32, 4, 4), 256, 0, stream>>>(Nbf, xqt_bf, x_q, gamma, out);
}